// Round 12
// baseline (312.199 us; speedup 1.0000x reference)
//
#include <hip/hip_runtime.h>
#include <hip/hip_bf16.h>

typedef __attribute__((ext_vector_type(4))) float f32x4;
typedef __attribute__((ext_vector_type(8))) short s16x8;

#define B_ 64
#define T_ 4096
#define H_ 512
#define E_ 512
#define BM 128         // T-rows per k2 block (= context chunk)
#define NCH (T_ / BM)  // 32 chunks per batch row

__device__ __forceinline__ short b2s(float x) {
  __hip_bfloat16 h = __float2bfloat16(x);  // RNE; pairs fuse to v_cvt_pk_bf16_f32
  return __builtin_bit_cast(short, h);
}

__device__ __forceinline__ s16x8 cvt8(f32x4 a, f32x4 b) {
  s16x8 r;
  r[0] = b2s(a[0]); r[1] = b2s(a[1]); r[2] = b2s(a[2]); r[3] = b2s(a[3]);
  r[4] = b2s(b[0]); r[5] = b2s(b[1]); r[6] = b2s(b[2]); r[7] = b2s(b[3]);
  return r;
}

__device__ __forceinline__ float bf2f(short s) {
  return __uint_as_float(((unsigned)(unsigned short)s) << 16);
}

__device__ __forceinline__ float fast_tanh(float x) {
  float e;
  asm("v_exp_f32 %0, %1" : "=v"(e) : "v"(x * 2.88539008177792681f));  // 2^(2x/ln2)
  float r;
  asm("v_rcp_f32 %0, %1" : "=v"(r) : "v"(e + 1.0f));
  return 1.0f - 2.0f * r;
}

// k0: fragment-major repack of W_e (rows 512..1023 of W_attn):
// frag(h16, s) is ONE contiguous 1-KiB block; lane i loads base+i*16B.
__global__ __launch_bounds__(512) void k0_fragpack(const float* __restrict__ W,
                                                   unsigned short* __restrict__ WtF) {
  const int h16 = blockIdx.x;   // 0..31
  const int s = blockIdx.y;     // 0..15
  const int tid = threadIdx.x;  // 0..511
  const int lane = tid >> 3, e = tid & 7;
  const int lr = lane & 15, lq = lane >> 4;
  const int k = s * 32 + lq * 8 + e;
  const int h = h16 * 16 + lr;
  WtF[(size_t)(h16 * 16 + s) * 512 + tid] =
      (unsigned short)b2s(W[(size_t)(512 + k) * H_ + h]);
}

// k1: projb[b][h] = b_attn[h] + sum_e hidden[b][e] * W_attn[e][h]
__global__ __launch_bounds__(512) void k1_projb(const float* __restrict__ hidden,
                                                const float* __restrict__ W,
                                                const float* __restrict__ b_attn,
                                                float* __restrict__ projb) {
  __shared__ float hid_s[H_];
  __shared__ float part[4][128];
  const int b = blockIdx.x, hg = blockIdx.y;
  const int tid = threadIdx.x;
  const int hl = tid & 127, es = tid >> 7;
  hid_s[tid] = hidden[b * H_ + tid];
  __syncthreads();
  const int h = hg * 128 + hl;
  const float* wp = W + (size_t)(es * 128) * H_ + h;
  float s = 0.0f;
  #pragma unroll 8
  for (int e = 0; e < 128; ++e) s = fmaf(hid_s[es * 128 + e], wp[(size_t)e * H_], s);
  part[es][hl] = s;
  __syncthreads();
  if (es == 0)
    projb[b * H_ + h] = b_attn[h] + part[0][hl] + part[1][hl] + part[2][hl] + part[3][hl];
}

// k2: fused logits + chunk-softmax + partial context.
// 512 thr = 8 waves (2T x 4H); block = 128T x 512H; wave tile 64T x 128H,
// acc[4][8]=128 AGPR (per-wave geometry identical to R11). A (enc, 128x512)
// cvt to bf16, staged in LDS ONCE (128 KB, swizzle chunk^=(row&7)). 16-step
// K-loop, ZERO barriers, reg ping-pong; B from fragment-major WtF (coalesced
// 1-KiB frags). BM=128 halves the per-block B traffic vs BM=64 (the L2-BW
// bound R11 hit). Epilogue context reads the bf16 A tile from LDS.
__global__ __launch_bounds__(512, 2) void k2_logits(
    const float* __restrict__ enc, const unsigned short* __restrict__ wtF,
    const float* __restrict__ projb, const float* __restrict__ vw,
    float* __restrict__ logits, float* __restrict__ mstat,
    float* __restrict__ partial) {
  __shared__ unsigned short a_s[BM * 512];  // 128 KiB, whole-K A tile (bf16)
  __shared__ float projb_s[H_];
  __shared__ float vw_s[H_];
  __shared__ float part[BM][4];
  __shared__ float lg_s[BM];
  __shared__ float comb[7][64][8];  // 14 KiB, context combine

  const int b = blockIdx.y;
  const int chunk = blockIdx.x;
  const int t0 = chunk * BM;
  const int tid = threadIdx.x;
  const int lane = tid & 63;
  const int w = tid >> 6;    // 0..7
  const int waveT = w >> 2;  // 0..1  (T half)
  const int waveH = w & 3;   // 0..3  (H slice)
  const int lr = lane & 15;
  const int lq = lane >> 4;

  projb_s[tid] = projb[b * H_ + tid];
  vw_s[tid] = vw[tid];

  const size_t row0 = (size_t)b * T_ + t0;

  // ---- fill A tile (once): 4 threads/row, 16 chunks (16B bf16) per thread ----
  {
    const int ra = tid >> 2, ca = tid & 3;
    const float* arow = enc + (row0 + ra) * (size_t)E_;
    unsigned short* adst = &a_s[ra * 512];
    #pragma unroll
    for (int jj = 0; jj < 16; ++jj) {
      const int c = ca + jj * 4;  // 16B chunk 0..63
      f32x4 v0 = *(const f32x4*)(arow + c * 8);
      f32x4 v1 = *(const f32x4*)(arow + c * 8 + 4);
      *(s16x8*)&adst[(c ^ (ra & 7)) * 8] = cvt8(v0, v1);
    }
  }
  __syncthreads();  // the ONLY pre-epilogue barrier

  // B: fragment-major; wave's H-slice waveH owns h16 = waveH*8 + nb
  const int whu = __builtin_amdgcn_readfirstlane(waveH);
  const unsigned short* wtW = wtF + ((size_t)whu * 8 * 16) * 512 + (size_t)lane * 8;
  const unsigned short* aBase = &a_s[0];

#define LOADB(dst, s)                                                        \
  _Pragma("unroll") for (int nb = 0; nb < 8; ++nb) dst[nb] =                 \
      *(const s16x8*)(wtW + ((size_t)(nb * 16 + (s)) << 9));
#define LOADA(dst, s)                                                        \
  _Pragma("unroll") for (int a = 0; a < 4; ++a) dst[a] =                     \
      *(const s16x8*)&aBase[(waveT * 64 + a * 16 + lr) * 512 +               \
                            (((s) * 4 + lq) ^ (lr & 7)) * 8];
#define MFMA32(af, bf)                                                       \
  __builtin_amdgcn_s_setprio(1);                                             \
  _Pragma("unroll") for (int a = 0; a < 4; ++a)                              \
  _Pragma("unroll") for (int nb = 0; nb < 8; ++nb) acc[a][nb] =              \
      __builtin_amdgcn_mfma_f32_16x16x32_bf16(af[a], bf[nb], acc[a][nb], 0, 0, 0); \
  __builtin_amdgcn_s_setprio(0);

  f32x4 acc[4][8] = {};
  s16x8 bA[8], bB[8], aA[4], aB[4];

  LOADA(aA, 0);
  LOADB(bA, 0);
  #pragma unroll
  for (int p = 0; p < 8; ++p) {
    const int s = 2 * p;
    LOADA(aB, s + 1);  // prefetch next step (counted waits only, no drain)
    LOADB(bB, s + 1);
    MFMA32(aA, bA);
    if (p < 7) {
      LOADA(aA, s + 2);
      LOADB(bA, s + 2);
    }
    MFMA32(aB, bB);
  }
#undef LOADA
#undef LOADB
#undef MFMA32

  // ---- logits: energy = tanh(acc + projb), partial = sum_h energy * vw ----
  #pragma unroll
  for (int a = 0; a < 4; ++a) {
    #pragma unroll
    for (int j = 0; j < 4; ++j) {
      float ssum = 0.0f;
      #pragma unroll
      for (int nb = 0; nb < 8; ++nb) {
        const int h = waveH * 128 + nb * 16 + lr;  // C/D: col = lane&15
        float x = acc[a][nb][j] + projb_s[h];
        ssum += fast_tanh(x) * vw_s[h];
      }
      ssum += __shfl_xor(ssum, 1);
      ssum += __shfl_xor(ssum, 2);
      ssum += __shfl_xor(ssum, 4);
      ssum += __shfl_xor(ssum, 8);
      if (lr == 0) part[waveT * 64 + a * 16 + lq * 4 + j][waveH] = ssum;
    }
  }
  __syncthreads();
  if (tid < BM) {
    float l = part[tid][0] + part[tid][1] + part[tid][2] + part[tid][3];
    lg_s[tid] = l;
    logits[(size_t)b * T_ + t0 + tid] = l;
  }
  __syncthreads();

  // ---- chunk softmax numerator + partial context from LDS bf16 A tile ----
  float m_c = -1e30f;
  #pragma unroll 8
  for (int t = 0; t < BM; ++t) m_c = fmaxf(m_c, lg_s[t]);

  const int cc = tid & 63;  // bf16 chunk column (8 e-values)
  const int tg = tid >> 6;  // 0..7, 16 t-rows each
  float a8[8] = {};
  #pragma unroll 4
  for (int i = 0; i < 16; ++i) {
    const int r = tg * 16 + i;
    float pw = __expf(lg_s[r] - m_c);
    s16x8 av = *(const s16x8*)&a_s[r * 512 + (cc ^ (r & 7)) * 8];
    #pragma unroll
    for (int e = 0; e < 8; ++e) a8[e] = fmaf(pw, bf2f(av[e]), a8[e]);
  }
  if (tg > 0) {
    #pragma unroll
    for (int e = 0; e < 8; ++e) comb[tg - 1][cc][e] = a8[e];
  }
  __syncthreads();
  if (tg == 0) {
    float* pp = partial + ((size_t)(b * NCH + chunk)) * E_ + cc * 8;
    #pragma unroll
    for (int e = 0; e < 8; ++e) {
      float v = a8[e];
      #pragma unroll
      for (int g = 0; g < 7; ++g) v += comb[g][cc][e];
      pp[e] = v;
    }
    if (tid == 0) mstat[b * NCH + chunk] = m_c;
  }
}

// k3: softmax over T per batch -> weights; also per-b (max, Z)
__global__ __launch_bounds__(256) void k3_softmax(const float* __restrict__ logits,
                                                  float* __restrict__ weights,
                                                  float* __restrict__ mz) {
  __shared__ float red[4];
  const int b = blockIdx.x;
  const int tid = threadIdx.x;
  const float* lg = logits + (size_t)b * T_;
  float v[16];
  float m = -1e30f;
  #pragma unroll
  for (int i = 0; i < 16; ++i) {
    v[i] = lg[tid + i * 256];
    m = fmaxf(m, v[i]);
  }
  #pragma unroll
  for (int d = 1; d < 64; d <<= 1) m = fmaxf(m, __shfl_xor(m, d));
  if ((tid & 63) == 0) red[tid >> 6] = m;
  __syncthreads();
  m = fmaxf(fmaxf(red[0], red[1]), fmaxf(red[2], red[3]));
  __syncthreads();
  float s = 0.0f;
  #pragma unroll
  for (int i = 0; i < 16; ++i) {
    v[i] = __expf(v[i] - m);
    s += v[i];
  }
  #pragma unroll
  for (int d = 1; d < 64; d <<= 1) s += __shfl_xor(s, d);
  if ((tid & 63) == 0) red[tid >> 6] = s;
  __syncthreads();
  s = red[0] + red[1] + red[2] + red[3];
  float inv = 1.0f / s;
  #pragma unroll
  for (int i = 0; i < 16; ++i) weights[(size_t)b * T_ + tid + i * 256] = v[i] * inv;
  if (tid == 0) {
    mz[b * 2] = m;
    mz[b * 2 + 1] = s;
  }
}

// k5: context = sum_c exp(m_c - m_b) * partial[b,c,:] / Z_b
__global__ __launch_bounds__(128) void k5_ctx_final(const float* __restrict__ partial,
                                                    const float* __restrict__ mstat,
                                                    const float* __restrict__ mz,
                                                    float* __restrict__ ctx) {
  __shared__ float sc[NCH];
  const int b = blockIdx.x;
  const int tid = threadIdx.x;
  const float m_b = mz[b * 2];
  const float invZ = 1.0f / mz[b * 2 + 1];
  if (tid < NCH) sc[tid] = __expf(mstat[b * NCH + tid] - m_b);
  __syncthreads();
  const float* pp = partial + (size_t)b * NCH * E_ + tid * 4;
  f32x4 s = {};
  #pragma unroll 8
  for (int c = 0; c < NCH; ++c) s += sc[c] * (*(const f32x4*)(pp + (size_t)c * E_));
  s *= invZ;
  *(f32x4*)(ctx + (size_t)b * E_ + tid * 4) = s;
}

extern "C" void kernel_launch(void* const* d_in, const int* in_sizes, int n_in,
                              void* d_out, int out_size, void* d_ws, size_t ws_size,
                              hipStream_t stream) {
  const float* hidden = (const float*)d_in[0];
  const float* enc = (const float*)d_in[1];
  const float* W_attn = (const float*)d_in[2];
  const float* b_attn = (const float*)d_in[3];
  const float* v_w = (const float*)d_in[4];

  float* out_ctx = (float*)d_out;                  // 64*512
  float* out_w = (float*)d_out + (size_t)B_ * H_;  // 64*4096

  char* ws = (char*)d_ws;
  unsigned short* WtF = (unsigned short*)ws;     // 512 KiB (fragment-major)
  float* projb = (float*)(ws + (512 << 10));     // 128 KiB
  float* logits = (float*)(ws + (640 << 10));    // 1 MiB
  float* mstat = (float*)(ws + (1664 << 10));    // 8 KiB (64*32 chunk maxes)
  float* mz = (float*)(ws + (1700 << 10));       // 512 B  (per-b max, Z)
  float* partial = (float*)(ws + (1728 << 10));  // 4 MiB  (64*32*512 fp32)

  k0_fragpack<<<dim3(32, 16), 512, 0, stream>>>(W_attn, WtF);
  k1_projb<<<dim3(64, 4), 512, 0, stream>>>(hidden, W_attn, b_attn, projb);
  k2_logits<<<dim3(NCH, B_), 512, 0, stream>>>(enc, WtF, projb, v_w, logits, mstat, partial);
  k3_softmax<<<B_, 256, 0, stream>>>(logits, out_w, mz);
  k5_ctx_final<<<B_, 128, 0, stream>>>(partial, mstat, mz, out_ctx);
}

// Round 13
// 296.783 us; speedup vs baseline: 1.0519x; 1.0519x over previous
//
#include <hip/hip_runtime.h>
#include <hip/hip_bf16.h>

typedef __attribute__((ext_vector_type(4))) float f32x4;
typedef __attribute__((ext_vector_type(8))) short s16x8;

#define B_ 64
#define T_ 4096
#define H_ 512
#define E_ 512
#define BM 64          // T-rows per k2 block (= context chunk)
#define NCH (T_ / BM)  // 64 chunks per batch row

__device__ __forceinline__ short b2s(float x) {
  __hip_bfloat16 h = __float2bfloat16(x);  // RNE; pairs fuse to v_cvt_pk_bf16_f32
  return __builtin_bit_cast(short, h);
}

__device__ __forceinline__ s16x8 cvt8(f32x4 a, f32x4 b) {
  s16x8 r;
  r[0] = b2s(a[0]); r[1] = b2s(a[1]); r[2] = b2s(a[2]); r[3] = b2s(a[3]);
  r[4] = b2s(b[0]); r[5] = b2s(b[1]); r[6] = b2s(b[2]); r[7] = b2s(b[3]);
  return r;
}

__device__ __forceinline__ float bf2f(short s) {
  return __uint_as_float(((unsigned)(unsigned short)s) << 16);
}

__device__ __forceinline__ float fast_tanh(float x) {
  float e;
  asm("v_exp_f32 %0, %1" : "=v"(e) : "v"(x * 2.88539008177792681f));  // 2^(2x/ln2)
  float r;
  asm("v_rcp_f32 %0, %1" : "=v"(r) : "v"(e + 1.0f));
  return 1.0f - 2.0f * r;
}

// k0: fragment-major repack of W_e (rows 512..1023 of W_attn):
// frag(h16, s) is ONE contiguous 1-KiB block; lane i loads base+i*16B.
__global__ __launch_bounds__(512) void k0_fragpack(const float* __restrict__ W,
                                                   unsigned short* __restrict__ WtF) {
  const int h16 = blockIdx.x;   // 0..31
  const int s = blockIdx.y;     // 0..15
  const int tid = threadIdx.x;  // 0..511
  const int lane = tid >> 3, e = tid & 7;
  const int lr = lane & 15, lq = lane >> 4;
  const int k = s * 32 + lq * 8 + e;
  const int h = h16 * 16 + lr;
  WtF[(size_t)(h16 * 16 + s) * 512 + tid] =
      (unsigned short)b2s(W[(size_t)(512 + k) * H_ + h]);
}

// k1: projb[b][h] = b_attn[h] + sum_e hidden[b][e] * W_attn[e][h]
__global__ __launch_bounds__(512) void k1_projb(const float* __restrict__ hidden,
                                                const float* __restrict__ W,
                                                const float* __restrict__ b_attn,
                                                float* __restrict__ projb) {
  __shared__ float hid_s[H_];
  __shared__ float part[4][128];
  const int b = blockIdx.x, hg = blockIdx.y;
  const int tid = threadIdx.x;
  const int hl = tid & 127, es = tid >> 7;
  hid_s[tid] = hidden[b * H_ + tid];
  __syncthreads();
  const int h = hg * 128 + hl;
  const float* wp = W + (size_t)(es * 128) * H_ + h;
  float s = 0.0f;
  #pragma unroll 8
  for (int e = 0; e < 128; ++e) s = fmaf(hid_s[es * 128 + e], wp[(size_t)e * H_], s);
  part[es][hl] = s;
  __syncthreads();
  if (es == 0)
    projb[b * H_ + h] = b_attn[h] + part[0][hl] + part[1][hl] + part[2][hl] + part[3][hl];
}

// k2: fused logits + chunk-softmax + partial context.
// 256 thr = 4 waves; block = 64T x 512H; wave tile 64T x 128H, acc[4][8]=128 AGPR.
// A-fill is INTERLEAVED into the K-loop (batch = 4 chunks = one K-step's data):
//   step s: ds_write batch s+1 (regs loaded at s-1), issue loads for batch s+2,
//   consume batch s via ds_read. Raw s_barrier + lgkmcnt(0) per step; all vmcnt
//   waits counted (fill loads issued BEFORE the 8 B-prefetch loads). This
//   smooths HBM demand (16 KB/CU/step) instead of 256-KB phase bursts.
// B from fragment-major WtF (coalesced 1-KiB frags), reg ping-pong.
// Epilogue context reads the bf16 A tile from LDS.
__global__ __launch_bounds__(256, 2) void k2_logits(
    const float* __restrict__ enc, const unsigned short* __restrict__ wtF,
    const float* __restrict__ projb, const float* __restrict__ vw,
    float* __restrict__ logits, float* __restrict__ mstat,
    float* __restrict__ partial) {
  __shared__ unsigned short a_s[BM * 512];  // 64 KiB, whole-K A tile (bf16)
  __shared__ float projb_s[H_];
  __shared__ float vw_s[H_];
  __shared__ float part[BM][4];
  __shared__ float lg_s[BM];
  __shared__ float comb[3][64][8];  // 6 KiB, context combine

  const int b = blockIdx.y;
  const int chunk = blockIdx.x;
  const int t0 = chunk * BM;
  const int tid = threadIdx.x;
  const int lane = tid & 63;
  const int w = tid >> 6;  // wave id = H-slice (0..3)
  const int lr = lane & 15;
  const int lq = lane >> 4;

  projb_s[tid] = projb[b * H_ + tid];
  projb_s[tid + 256] = projb[b * H_ + tid + 256];
  vw_s[tid] = vw[tid];
  vw_s[tid + 256] = vw[tid + 256];

  const size_t row0 = (size_t)b * T_ + t0;

  // fill geometry: 1 slot (32 B fp32 -> 16 B bf16) per thread per batch
  const int ra = tid >> 2, ca = tid & 3;  // row, chunk-in-batch
  const float* aSrc = enc + (row0 + ra) * (size_t)E_;
  unsigned short* aRow = &a_s[ra * 512];

#define LDFILL(dst, n)                                        \
  {                                                           \
    const int c_ = (n)*4 + ca;                                \
    dst##0 = *(const f32x4*)(aSrc + c_ * 8);                  \
    dst##1 = *(const f32x4*)(aSrc + c_ * 8 + 4);              \
  }
#define WRFILL(src, n)                                        \
  {                                                           \
    const int c_ = (n)*4 + ca;                                \
    *(s16x8*)&aRow[(c_ ^ (ra & 7)) * 8] = cvt8(src##0, src##1); \
  }

  // ---- prologue: fill batches 0,1 directly; prefetch B(0) ----
  {
    f32x4 p0, p1;
    LDFILL(p, 0); WRFILL(p, 0);
    LDFILL(p, 1); WRFILL(p, 1);
  }

  const int wu = __builtin_amdgcn_readfirstlane(w);
  const unsigned short* wtW = wtF + ((size_t)wu * 8 * 16) * 512 + (size_t)lane * 8;
  const unsigned short* aBase = &a_s[0];

#define LOADB(dst, s)                                                        \
  _Pragma("unroll") for (int nb = 0; nb < 8; ++nb) dst[nb] =                 \
      *(const s16x8*)(wtW + ((size_t)(nb * 16 + (s)) << 9));
#define LOADA(dst, s)                                                        \
  _Pragma("unroll") for (int a = 0; a < 4; ++a) dst[a] =                     \
      *(const s16x8*)&aBase[(a * 16 + lr) * 512 + (((s) * 4 + lq) ^ (lr & 7)) * 8];
#define MFMA32(af, bf)                                                       \
  __builtin_amdgcn_s_setprio(1);                                             \
  _Pragma("unroll") for (int a = 0; a < 4; ++a)                              \
  _Pragma("unroll") for (int nb = 0; nb < 8; ++nb) acc[a][nb] =              \
      __builtin_amdgcn_mfma_f32_16x16x32_bf16(af[a], bf[nb], acc[a][nb], 0, 0, 0); \
  __builtin_amdgcn_s_setprio(0);
#define STEPSYNC                                                             \
  asm volatile("s_waitcnt lgkmcnt(0)" ::: "memory");                         \
  __builtin_amdgcn_s_barrier();                                              \
  __builtin_amdgcn_sched_barrier(0);

  f32x4 acc[4][8] = {};
  s16x8 bA[8], bB[8], aCur[4];
  f32x4 fA0, fA1, fB0, fB1;  // two alternating fill-reg sets

  LOADB(bA, 0);
  __syncthreads();  // prologue drain (batches 0,1 visible)

  #pragma unroll
  for (int p = 0; p < 8; ++p) {
    const int s = 2 * p;
    // ======== even step s ========
    if (s <= 13) LDFILL(fA, s + 2);   // VM oldest this step
    if (s <= 14) LOADB(bB, s + 1);    // VM newest
    LOADA(aCur, s);
    if (s >= 2) WRFILL(fB, s + 1);    // regs from odd step s-1; vmcnt counted
    MFMA32(aCur, bA);
    STEPSYNC
    // ======== odd step s+1 ========
    if (s + 1 <= 13) LDFILL(fB, s + 3);
    if (s + 1 <= 14) LOADB(bA, s + 2);
    LOADA(aCur, s + 1);
    if (s + 1 <= 14) WRFILL(fA, s + 2);  // regs from even step s
    MFMA32(aCur, bB);
    if (p < 7) { STEPSYNC }
  }
#undef LOADA
#undef LOADB
#undef MFMA32
#undef STEPSYNC
#undef LDFILL
#undef WRFILL

  // ---- logits: energy = tanh(acc + projb), partial = sum_h energy * vw ----
  #pragma unroll
  for (int a = 0; a < 4; ++a) {
    #pragma unroll
    for (int j = 0; j < 4; ++j) {
      float ssum = 0.0f;
      #pragma unroll
      for (int nb = 0; nb < 8; ++nb) {
        const int h = w * 128 + nb * 16 + lr;  // C/D: col = lane&15
        float x = acc[a][nb][j] + projb_s[h];
        ssum += fast_tanh(x) * vw_s[h];
      }
      ssum += __shfl_xor(ssum, 1);
      ssum += __shfl_xor(ssum, 2);
      ssum += __shfl_xor(ssum, 4);
      ssum += __shfl_xor(ssum, 8);
      if (lr == 0) part[a * 16 + lq * 4 + j][w] = ssum;  // C/D: row = lq*4+j
    }
  }
  __syncthreads();
  if (tid < BM) {
    float l = part[tid][0] + part[tid][1] + part[tid][2] + part[tid][3];
    lg_s[tid] = l;
    logits[(size_t)b * T_ + t0 + tid] = l;
  }
  __syncthreads();

  // ---- chunk softmax numerator + partial context from LDS bf16 A tile ----
  float m_c = -1e30f;
  #pragma unroll 8
  for (int t = 0; t < BM; ++t) m_c = fmaxf(m_c, lg_s[t]);

  const int cc = tid & 63;  // bf16 chunk column (8 e-values)
  const int tg = tid >> 6;  // 0..3, 16 t-rows each
  float a8[8] = {};
  #pragma unroll 4
  for (int i = 0; i < 16; ++i) {
    const int r = tg * 16 + i;
    float pw = __expf(lg_s[r] - m_c);
    s16x8 av = *(const s16x8*)&a_s[r * 512 + (cc ^ (r & 7)) * 8];
    #pragma unroll
    for (int e = 0; e < 8; ++e) a8[e] = fmaf(pw, bf2f(av[e]), a8[e]);
  }
  if (tg > 0) {
    #pragma unroll
    for (int e = 0; e < 8; ++e) comb[tg - 1][cc][e] = a8[e];
  }
  __syncthreads();
  if (tg == 0) {
    float* pp = partial + ((size_t)(b * NCH + chunk)) * E_ + cc * 8;
    #pragma unroll
    for (int e = 0; e < 8; ++e)
      pp[e] = a8[e] + comb[0][cc][e] + comb[1][cc][e] + comb[2][cc][e];
    if (tid == 0) mstat[b * NCH + chunk] = m_c;
  }
}

// k3: softmax over T per batch -> weights; also per-b (max, Z)
__global__ __launch_bounds__(256) void k3_softmax(const float* __restrict__ logits,
                                                  float* __restrict__ weights,
                                                  float* __restrict__ mz) {
  __shared__ float red[4];
  const int b = blockIdx.x;
  const int tid = threadIdx.x;
  const float* lg = logits + (size_t)b * T_;
  float v[16];
  float m = -1e30f;
  #pragma unroll
  for (int i = 0; i < 16; ++i) {
    v[i] = lg[tid + i * 256];
    m = fmaxf(m, v[i]);
  }
  #pragma unroll
  for (int d = 1; d < 64; d <<= 1) m = fmaxf(m, __shfl_xor(m, d));
  if ((tid & 63) == 0) red[tid >> 6] = m;
  __syncthreads();
  m = fmaxf(fmaxf(red[0], red[1]), fmaxf(red[2], red[3]));
  __syncthreads();
  float s = 0.0f;
  #pragma unroll
  for (int i = 0; i < 16; ++i) {
    v[i] = __expf(v[i] - m);
    s += v[i];
  }
  #pragma unroll
  for (int d = 1; d < 64; d <<= 1) s += __shfl_xor(s, d);
  if ((tid & 63) == 0) red[tid >> 6] = s;
  __syncthreads();
  s = red[0] + red[1] + red[2] + red[3];
  float inv = 1.0f / s;
  #pragma unroll
  for (int i = 0; i < 16; ++i) weights[(size_t)b * T_ + tid + i * 256] = v[i] * inv;
  if (tid == 0) {
    mz[b * 2] = m;
    mz[b * 2 + 1] = s;
  }
}

// k5: context = sum_c exp(m_c - m_b) * partial[b,c,:] / Z_b
__global__ __launch_bounds__(128) void k5_ctx_final(const float* __restrict__ partial,
                                                    const float* __restrict__ mstat,
                                                    const float* __restrict__ mz,
                                                    float* __restrict__ ctx) {
  __shared__ float sc[NCH];
  const int b = blockIdx.x;
  const int tid = threadIdx.x;
  const float m_b = mz[b * 2];
  const float invZ = 1.0f / mz[b * 2 + 1];
  if (tid < NCH) sc[tid] = __expf(mstat[b * NCH + tid] - m_b);
  __syncthreads();
  const float* pp = partial + (size_t)b * NCH * E_ + tid * 4;
  f32x4 s = {};
  #pragma unroll 8
  for (int c = 0; c < NCH; ++c) s += sc[c] * (*(const f32x4*)(pp + (size_t)c * E_));
  s *= invZ;
  *(f32x4*)(ctx + (size_t)b * E_ + tid * 4) = s;
}

extern "C" void kernel_launch(void* const* d_in, const int* in_sizes, int n_in,
                              void* d_out, int out_size, void* d_ws, size_t ws_size,
                              hipStream_t stream) {
  const float* hidden = (const float*)d_in[0];
  const float* enc = (const float*)d_in[1];
  const float* W_attn = (const float*)d_in[2];
  const float* b_attn = (const float*)d_in[3];
  const float* v_w = (const float*)d_in[4];

  float* out_ctx = (float*)d_out;                  // 64*512
  float* out_w = (float*)d_out + (size_t)B_ * H_;  // 64*4096

  char* ws = (char*)d_ws;
  unsigned short* WtF = (unsigned short*)ws;     // 512 KiB (fragment-major)
  float* projb = (float*)(ws + (512 << 10));     // 128 KiB
  float* logits = (float*)(ws + (640 << 10));    // 1 MiB
  float* mstat = (float*)(ws + (1664 << 10));    // 16 KiB (64*64 chunk maxes)
  float* mz = (float*)(ws + (1700 << 10));       // 512 B  (per-b max, Z)
  float* partial = (float*)(ws + (1728 << 10));  // 8 MiB  (64*64*512 fp32)

  k0_fragpack<<<dim3(32, 16), 512, 0, stream>>>(W_attn, WtF);
  k1_projb<<<dim3(64, 4), 512, 0, stream>>>(hidden, W_attn, b_attn, projb);
  k2_logits<<<dim3(NCH, B_), 256, 0, stream>>>(enc, WtF, projb, v_w, logits, mstat, partial);
  k3_softmax<<<B_, 256, 0, stream>>>(logits, out_w, mz);
  k5_ctx_final<<<B_, 128, 0, stream>>>(partial, mstat, mz, out_ctx);
}

// Round 14
// 255.095 us; speedup vs baseline: 1.2239x; 1.1634x over previous
//
#include <hip/hip_runtime.h>
#include <hip/hip_bf16.h>

typedef __attribute__((ext_vector_type(4))) float f32x4;
typedef __attribute__((ext_vector_type(8))) short s16x8;

#define B_ 64
#define T_ 4096
#define H_ 512
#define E_ 512
#define BM 64          // T-rows per k2 block (= context chunk)
#define NCH (T_ / BM)  // 64 chunks per batch row

__device__ __forceinline__ short b2s(float x) {
  __hip_bfloat16 h = __float2bfloat16(x);  // RNE; pairs fuse to v_cvt_pk_bf16_f32
  return __builtin_bit_cast(short, h);
}

__device__ __forceinline__ s16x8 cvt8(f32x4 a, f32x4 b) {
  s16x8 r;
  r[0] = b2s(a[0]); r[1] = b2s(a[1]); r[2] = b2s(a[2]); r[3] = b2s(a[3]);
  r[4] = b2s(b[0]); r[5] = b2s(b[1]); r[6] = b2s(b[2]); r[7] = b2s(b[3]);
  return r;
}

__device__ __forceinline__ float bf2f(short s) {
  return __uint_as_float(((unsigned)(unsigned short)s) << 16);
}

__device__ __forceinline__ float fast_tanh(float x) {
  float e;
  asm("v_exp_f32 %0, %1" : "=v"(e) : "v"(x * 2.88539008177792681f));  // 2^(2x/ln2)
  float r;
  asm("v_rcp_f32 %0, %1" : "=v"(r) : "v"(e + 1.0f));
  return 1.0f - 2.0f * r;
}

// k0: fragment-major repack of W_e (rows 512..1023 of W_attn):
// frag(h16, s) is ONE contiguous 1-KiB block; lane i loads base+i*16B.
__global__ __launch_bounds__(512) void k0_fragpack(const float* __restrict__ W,
                                                   unsigned short* __restrict__ WtF) {
  const int h16 = blockIdx.x;   // 0..31
  const int s = blockIdx.y;     // 0..15
  const int tid = threadIdx.x;  // 0..511
  const int lane = tid >> 3, e = tid & 7;
  const int lr = lane & 15, lq = lane >> 4;
  const int k = s * 32 + lq * 8 + e;
  const int h = h16 * 16 + lr;
  WtF[(size_t)(h16 * 16 + s) * 512 + tid] =
      (unsigned short)b2s(W[(size_t)(512 + k) * H_ + h]);
}

// k1: projb[b][h] = b_attn[h] + sum_e hidden[b][e] * W_attn[e][h]
__global__ __launch_bounds__(512) void k1_projb(const float* __restrict__ hidden,
                                                const float* __restrict__ W,
                                                const float* __restrict__ b_attn,
                                                float* __restrict__ projb) {
  __shared__ float hid_s[H_];
  __shared__ float part[4][128];
  const int b = blockIdx.x, hg = blockIdx.y;
  const int tid = threadIdx.x;
  const int hl = tid & 127, es = tid >> 7;
  hid_s[tid] = hidden[b * H_ + tid];
  __syncthreads();
  const int h = hg * 128 + hl;
  const float* wp = W + (size_t)(es * 128) * H_ + h;
  float s = 0.0f;
  #pragma unroll 8
  for (int e = 0; e < 128; ++e) s = fmaf(hid_s[es * 128 + e], wp[(size_t)e * H_], s);
  part[es][hl] = s;
  __syncthreads();
  if (es == 0)
    projb[b * H_ + h] = b_attn[h] + part[0][hl] + part[1][hl] + part[2][hl] + part[3][hl];
}

// k2: fused logits + chunk-softmax + partial context.
// 256 thr = 4 waves; block = 64T x 512H; wave tile 64T x 128H, acc[4][8]=128 AGPR.
// HALF-TILE PIPELINE, zero per-step barriers (R11's drift loop + overlap):
//   prologue fills K-chunks 0..31 (32 KB); steps 0..7 consume them while the
//   fill of chunks 32..63 is interleaved (1 slot/step: WRFILL(prev); LDFILL(cur),
//   load->write distance = 1 MFMA cluster ~1240cyc > HBM latency; writes go to
//   the INACTIVE half so no barrier). ONE mid-loop lgkmcnt(0)+s_barrier; steps
//   8..15 are the pure drift body. Fill loads issued AFTER each step's B loads
//   so in-order vmcnt decrement never blocks B-consumers on HBM.
// B from fragment-major WtF (coalesced 1-KiB frags), reg ping-pong; A single
// set (aCur) read from LDS just before MFMA (saves 16 VGPR; ~240 total regs).
__global__ __launch_bounds__(256, 2) void k2_logits(
    const float* __restrict__ enc, const unsigned short* __restrict__ wtF,
    const float* __restrict__ projb, const float* __restrict__ vw,
    float* __restrict__ logits, float* __restrict__ mstat,
    float* __restrict__ partial) {
  __shared__ unsigned short a_s[BM * 512];  // 64 KiB, whole-K A tile (bf16)
  __shared__ float projb_s[H_];
  __shared__ float vw_s[H_];
  __shared__ float part[BM][4];
  __shared__ float lg_s[BM];
  __shared__ float comb[3][64][8];  // 6 KiB, context combine

  const int b = blockIdx.y;
  const int chunk = blockIdx.x;
  const int t0 = chunk * BM;
  const int tid = threadIdx.x;
  const int lane = tid & 63;
  const int w = tid >> 6;  // wave id = H-slice (0..3)
  const int lr = lane & 15;
  const int lq = lane >> 4;

  projb_s[tid] = projb[b * H_ + tid];
  projb_s[tid + 256] = projb[b * H_ + tid + 256];
  vw_s[tid] = vw[tid];
  vw_s[tid + 256] = vw[tid + 256];

  const size_t row0 = (size_t)b * T_ + t0;

  // fill geometry: thread owns (row ra, chunk-slot ca); chunk = 16B of bf16
  const int ra = tid >> 2, ca = tid & 3;
  const float* aSrc = enc + (row0 + ra) * (size_t)E_;
  unsigned short* aRow = &a_s[ra * 512];

  // ---- prologue: fill first half (chunks 0..31), two 4-slot batches ----
  {
    f32x4 g0[8];
    #pragma unroll
    for (int jj = 0; jj < 4; ++jj) {
      const int c = ca + jj * 4;
      g0[2 * jj] = *(const f32x4*)(aSrc + c * 8);
      g0[2 * jj + 1] = *(const f32x4*)(aSrc + c * 8 + 4);
    }
    #pragma unroll
    for (int jj = 0; jj < 4; ++jj) {
      const int c = ca + jj * 4;
      *(s16x8*)&aRow[(c ^ (ra & 7)) * 8] = cvt8(g0[2 * jj], g0[2 * jj + 1]);
    }
    #pragma unroll
    for (int jj = 4; jj < 8; ++jj) {
      const int c = ca + jj * 4;
      g0[2 * (jj - 4)] = *(const f32x4*)(aSrc + c * 8);
      g0[2 * (jj - 4) + 1] = *(const f32x4*)(aSrc + c * 8 + 4);
    }
    #pragma unroll
    for (int jj = 4; jj < 8; ++jj) {
      const int c = ca + jj * 4;
      *(s16x8*)&aRow[(c ^ (ra & 7)) * 8] = cvt8(g0[2 * (jj - 4)], g0[2 * (jj - 4) + 1]);
    }
  }

  const int wu = __builtin_amdgcn_readfirstlane(w);
  const unsigned short* wtW = wtF + ((size_t)wu * 8 * 16) * 512 + (size_t)lane * 8;
  const unsigned short* aBase = &a_s[0];

#define LOADB(dst, s)                                                        \
  _Pragma("unroll") for (int nb = 0; nb < 8; ++nb) dst[nb] =                 \
      *(const s16x8*)(wtW + ((size_t)(nb * 16 + (s)) << 9));
#define LOADA(dst, s)                                                        \
  _Pragma("unroll") for (int a = 0; a < 4; ++a) dst[a] =                     \
      *(const s16x8*)&aBase[(a * 16 + lr) * 512 + (((s) * 4 + lq) ^ (lr & 7)) * 8];
#define MFMA32(af, bf)                                                       \
  __builtin_amdgcn_s_setprio(1);                                             \
  _Pragma("unroll") for (int a = 0; a < 4; ++a)                              \
  _Pragma("unroll") for (int nb = 0; nb < 8; ++nb) acc[a][nb] =              \
      __builtin_amdgcn_mfma_f32_16x16x32_bf16(af[a], bf[nb], acc[a][nb], 0, 0, 0); \
  __builtin_amdgcn_s_setprio(0);
// slot n (0..7) <-> chunk 32 + 4n + ca (second half)
#define LDFILL(n)                                                            \
  {                                                                          \
    const int c_ = 32 + (n)*4 + ca;                                          \
    f0 = *(const f32x4*)(aSrc + c_ * 8);                                     \
    f1 = *(const f32x4*)(aSrc + c_ * 8 + 4);                                 \
  }
#define WRFILL(n)                                                            \
  {                                                                          \
    const int c_ = 32 + (n)*4 + ca;                                          \
    *(s16x8*)&aRow[(c_ ^ (ra & 7)) * 8] = cvt8(f0, f1);                      \
  }

  f32x4 acc[4][8] = {};
  s16x8 bA[8], bB[8], aCur[4];
  f32x4 f0, f1;  // single fill set (8 VGPR)

  LOADB(bA, 0);
  __syncthreads();  // first half visible

  // ---- first half: steps 0..7, interleaved second-half fill ----
  #pragma unroll
  for (int p = 0; p < 4; ++p) {
    const int s = 2 * p;
    // even step s
    LOADB(bB, s + 1);
    LOADA(aCur, s);
    if (p > 0) WRFILL(s - 1);  // loaded 1 cluster ago
    LDFILL(s);                 // newest VM ops of this step
    MFMA32(aCur, bA);
    // odd step s+1
    if (p < 3) LOADB(bA, s + 2);
    LOADA(aCur, s + 1);
    WRFILL(s);                 // 1 MFMA cluster after its load
    LDFILL(s + 1);
    MFMA32(aCur, bB);
  }
  WRFILL(7);
  asm volatile("s_waitcnt lgkmcnt(0)" ::: "memory");
  __builtin_amdgcn_s_barrier();  // second half now visible to all waves
  __builtin_amdgcn_sched_barrier(0);

  // ---- second half: steps 8..15, pure drift body ----
  LOADB(bA, 8);
  #pragma unroll
  for (int p = 0; p < 4; ++p) {
    const int s = 8 + 2 * p;
    LOADB(bB, s + 1);
    LOADA(aCur, s);
    MFMA32(aCur, bA);
    if (p < 3) LOADB(bA, s + 2);
    LOADA(aCur, s + 1);
    MFMA32(aCur, bB);
  }
#undef LOADA
#undef LOADB
#undef MFMA32
#undef LDFILL
#undef WRFILL

  // ---- logits: energy = tanh(acc + projb), partial = sum_h energy * vw ----
  #pragma unroll
  for (int a = 0; a < 4; ++a) {
    #pragma unroll
    for (int j = 0; j < 4; ++j) {
      float ssum = 0.0f;
      #pragma unroll
      for (int nb = 0; nb < 8; ++nb) {
        const int h = w * 128 + nb * 16 + lr;  // C/D: col = lane&15
        float x = acc[a][nb][j] + projb_s[h];
        ssum += fast_tanh(x) * vw_s[h];
      }
      ssum += __shfl_xor(ssum, 1);
      ssum += __shfl_xor(ssum, 2);
      ssum += __shfl_xor(ssum, 4);
      ssum += __shfl_xor(ssum, 8);
      if (lr == 0) part[a * 16 + lq * 4 + j][w] = ssum;  // C/D: row = lq*4+j
    }
  }
  __syncthreads();
  if (tid < BM) {
    float l = part[tid][0] + part[tid][1] + part[tid][2] + part[tid][3];
    lg_s[tid] = l;
    logits[(size_t)b * T_ + t0 + tid] = l;
  }
  __syncthreads();

  // ---- chunk softmax numerator + partial context from LDS bf16 A tile ----
  float m_c = -1e30f;
  #pragma unroll 8
  for (int t = 0; t < BM; ++t) m_c = fmaxf(m_c, lg_s[t]);

  const int cc = tid & 63;  // bf16 chunk column (8 e-values)
  const int tg = tid >> 6;  // 0..3, 16 t-rows each
  float a8[8] = {};
  #pragma unroll 4
  for (int i = 0; i < 16; ++i) {
    const int r = tg * 16 + i;
    float pw = __expf(lg_s[r] - m_c);
    s16x8 av = *(const s16x8*)&a_s[r * 512 + (cc ^ (r & 7)) * 8];
    #pragma unroll
    for (int e = 0; e < 8; ++e) a8[e] = fmaf(pw, bf2f(av[e]), a8[e]);
  }
  if (tg > 0) {
    #pragma unroll
    for (int e = 0; e < 8; ++e) comb[tg - 1][cc][e] = a8[e];
  }
  __syncthreads();
  if (tg == 0) {
    float* pp = partial + ((size_t)(b * NCH + chunk)) * E_ + cc * 8;
    #pragma unroll
    for (int e = 0; e < 8; ++e)
      pp[e] = a8[e] + comb[0][cc][e] + comb[1][cc][e] + comb[2][cc][e];
    if (tid == 0) mstat[b * NCH + chunk] = m_c;
  }
}

// k3: softmax over T per batch -> weights; also per-b (max, Z)
__global__ __launch_bounds__(256) void k3_softmax(const float* __restrict__ logits,
                                                  float* __restrict__ weights,
                                                  float* __restrict__ mz) {
  __shared__ float red[4];
  const int b = blockIdx.x;
  const int tid = threadIdx.x;
  const float* lg = logits + (size_t)b * T_;
  float v[16];
  float m = -1e30f;
  #pragma unroll
  for (int i = 0; i < 16; ++i) {
    v[i] = lg[tid + i * 256];
    m = fmaxf(m, v[i]);
  }
  #pragma unroll
  for (int d = 1; d < 64; d <<= 1) m = fmaxf(m, __shfl_xor(m, d));
  if ((tid & 63) == 0) red[tid >> 6] = m;
  __syncthreads();
  m = fmaxf(fmaxf(red[0], red[1]), fmaxf(red[2], red[3]));
  __syncthreads();
  float s = 0.0f;
  #pragma unroll
  for (int i = 0; i < 16; ++i) {
    v[i] = __expf(v[i] - m);
    s += v[i];
  }
  #pragma unroll
  for (int d = 1; d < 64; d <<= 1) s += __shfl_xor(s, d);
  if ((tid & 63) == 0) red[tid >> 6] = s;
  __syncthreads();
  s = red[0] + red[1] + red[2] + red[3];
  float inv = 1.0f / s;
  #pragma unroll
  for (int i = 0; i < 16; ++i) weights[(size_t)b * T_ + tid + i * 256] = v[i] * inv;
  if (tid == 0) {
    mz[b * 2] = m;
    mz[b * 2 + 1] = s;
  }
}

// k5: context = sum_c exp(m_c - m_b) * partial[b,c,:] / Z_b
__global__ __launch_bounds__(128) void k5_ctx_final(const float* __restrict__ partial,
                                                    const float* __restrict__ mstat,
                                                    const float* __restrict__ mz,
                                                    float* __restrict__ ctx) {
  __shared__ float sc[NCH];
  const int b = blockIdx.x;
  const int tid = threadIdx.x;
  const float m_b = mz[b * 2];
  const float invZ = 1.0f / mz[b * 2 + 1];
  if (tid < NCH) sc[tid] = __expf(mstat[b * NCH + tid] - m_b);
  __syncthreads();
  const float* pp = partial + (size_t)b * NCH * E_ + tid * 4;
  f32x4 s = {};
  #pragma unroll 8
  for (int c = 0; c < NCH; ++c) s += sc[c] * (*(const f32x4*)(pp + (size_t)c * E_));
  s *= invZ;
  *(f32x4*)(ctx + (size_t)b * E_ + tid * 4) = s;
}

extern "C" void kernel_launch(void* const* d_in, const int* in_sizes, int n_in,
                              void* d_out, int out_size, void* d_ws, size_t ws_size,
                              hipStream_t stream) {
  const float* hidden = (const float*)d_in[0];
  const float* enc = (const float*)d_in[1];
  const float* W_attn = (const float*)d_in[2];
  const float* b_attn = (const float*)d_in[3];
  const float* v_w = (const float*)d_in[4];

  float* out_ctx = (float*)d_out;                  // 64*512
  float* out_w = (float*)d_out + (size_t)B_ * H_;  // 64*4096

  char* ws = (char*)d_ws;
  unsigned short* WtF = (unsigned short*)ws;     // 512 KiB (fragment-major)
  float* projb = (float*)(ws + (512 << 10));     // 128 KiB
  float* logits = (float*)(ws + (640 << 10));    // 1 MiB
  float* mstat = (float*)(ws + (1664 << 10));    // 16 KiB (64*64 chunk maxes)
  float* mz = (float*)(ws + (1700 << 10));       // 512 B  (per-b max, Z)
  float* partial = (float*)(ws + (1728 << 10));  // 8 MiB  (64*64*512 fp32)

  k0_fragpack<<<dim3(32, 16), 512, 0, stream>>>(W_attn, WtF);
  k1_projb<<<dim3(64, 4), 512, 0, stream>>>(hidden, W_attn, b_attn, projb);
  k2_logits<<<dim3(NCH, B_), 256, 0, stream>>>(enc, WtF, projb, v_w, logits, mstat, partial);
  k3_softmax<<<B_, 256, 0, stream>>>(logits, out_w, mz);
  k5_ctx_final<<<B_, 128, 0, stream>>>(partial, mstat, mz, out_ctx);
}